// Round 20
// baseline (601.474 us; speedup 1.0000x reference)
//
#include <hip/hip_runtime.h>
#include <math.h>

#define HH 192
#define WW 192
#define HWSZ (HH*WW)
#define BB 4

typedef __attribute__((ext_vector_type(8))) short bf16x8;
typedef __attribute__((ext_vector_type(4))) float f32x4;

__device__ __forceinline__ unsigned short f2bf(float f) {
    unsigned int u = __float_as_uint(f);
    u = (u + 0x7FFFu + ((u >> 16) & 1u)) >> 16;
    return (unsigned short)u;
}
__device__ __forceinline__ float bf2f(unsigned short s) {
    return __uint_as_float(((unsigned int)s) << 16);
}

// ---------- merged weight prep: 6 convs + dcn in ONE launch ----------
__global__ void prep_all(
    const float* __restrict__ head_w, const float* __restrict__ c1w1,
    const float* __restrict__ c1w2,   const float* __restrict__ aux_w,
    const float* __restrict__ fw1,    const float* __restrict__ fw2,
    const float* __restrict__ dcn_w,
    unsigned short* __restrict__ wb_head, unsigned short* __restrict__ wb_c1w1,
    unsigned short* __restrict__ wb_c1w2, unsigned short* __restrict__ wb_aux,
    unsigned short* __restrict__ wb_fw1,  unsigned short* __restrict__ wb_fw2,
    unsigned short* __restrict__ wdefb2)
{
    int idx = blockIdx.x * 256 + threadIdx.x;
    const float* w; unsigned short* wb; int cout, cin;
    if (idx < 165888)                 { w = head_w; wb = wb_head; cout = 144; cin = 128; }
    else if ((idx -= 165888) < 73728) { w = c1w1;   wb = wb_c1w1; cout = 128; cin = 64;  }
    else if ((idx -= 73728) < 147456) { w = c1w2;   wb = wb_c1w2; cout = 128; cin = 128; }
    else if ((idx -= 147456) < 73728) { w = aux_w;  wb = wb_aux;  cout = 64;  cin = 128; }
    else if ((idx -= 73728) < 73728)  { w = fw1;    wb = wb_fw1;  cout = 64;  cin = 128; }
    else if ((idx -= 73728) < 36864)  { w = fw2;    wb = wb_fw2;  cout = 64;  cin = 64;  }
    else if ((idx -= 36864) < 36864) {
        int o = idx / 576, rem = idx % 576;
        int c = rem / 9, k = rem - c * 9;
        int K = k * 64 + c;
        wdefb2[((size_t)((K >> 5) * 64 + o)) * 32 + (K & 31)] = f2bf(dcn_w[idx]);
        return;
    } else return;
    int o = idx / (cin * 9);
    int rem = idx - o * cin * 9;
    int c = rem / 9;
    int t = rem - c * 9;
    int nch = cin >> 5;
    wb[((t * nch + (c >> 5)) * cout + o) * 32 + (c & 31)] = f2bf(w[idx]);
}

// ---------- transpose f32 NCHW -> bf16 cl32 (mv+ref) AND cl8 (ref only) ----------
__global__ __launch_bounds__(256) void transpose_all(
    const float* __restrict__ mv, const float* __restrict__ ref,
    unsigned short* __restrict__ mvb, unsigned short* __restrict__ refb,
    unsigned short* __restrict__ refb8)
{
    __shared__ float tile[32][68];
    const int tid = threadIdx.x;
    int bz = blockIdx.z;
    const float* in; unsigned short* outb;
    bool isRef = (bz >= 16);
    int bzr = isRef ? bz - 16 : bz;
    if (isRef) { in = ref; outb = refb; }
    else       { in = mv;  outb = mvb;  }
    const int y = blockIdx.y;
    const int x0 = blockIdx.x * 64;
#pragma unroll
    for (int it = 0; it < 2; ++it) {
        int u = tid + it * 256;
        int c = u >> 4, q = u & 15;
        float4 v = *(const float4*)(in + (((size_t)bzr * 32 + c) * HH + y) * WW + x0 + q * 4);
        *(float4*)&tile[c][q * 4] = v;
    }
    __syncthreads();
    const int pxl = tid >> 2, c8 = tid & 3;
    bf16x8 ov;
#pragma unroll
    for (int j = 0; j < 8; ++j) ov[j] = (short)f2bf(tile[c8 * 8 + j][pxl]);
    *(bf16x8*)(outb + (((size_t)bzr * HH + y) * WW + x0 + pxl) * 32 + c8 * 8) = ov;
    if (isRef) {
        *(bf16x8*)(refb8 + ((size_t)(bzr * 4 + c8) * HWSZ + (size_t)y * WW + x0 + pxl) * 8) = ov;
    }
}

// ---------- 3x3 conv v10: input AND weights staged in LDS per chunk ----------
template<int CIN, int COUT_TILE, bool RELU, int EPI>
__global__ __launch_bounds__(256, 3) void conv3x3_v10(
    const unsigned short* __restrict__ in, const unsigned short* __restrict__ wb,
    const float* __restrict__ bias, void* __restrict__ outp,
    int cTot, int ocBase, int nOc, int coutFull, int nPerXcd)
{
    constexpr int NCH = CIN / 32;
    constexpr int NOC = COUT_TILE / 16;
    constexpr int WGR = 36 * COUT_TILE;
    __shared__ __align__(16) unsigned short sx[6 * 72 * 32];
    __shared__ __align__(16) unsigned short sw[288 * COUT_TILE];

    const int tid = threadIdx.x;
    const int d = blockIdx.x;
    const int w = (d & 7) * nPerXcd + (d >> 3);
    const int ocT = (w % nOc) * COUT_TILE;
    int t = w / nOc;
    const int x0 = (t % 3) * 64; t /= 3;
    const int y0 = (t % 48) * 4;
    const int b  = t / 48;
    const int wv = tid >> 6, lane = tid & 63;
    const int l15 = lane & 15, kg = lane >> 4;

    f32x4 acc[NOC][4];
#pragma unroll
    for (int oc = 0; oc < NOC; ++oc)
#pragma unroll
        for (int s = 0; s < 4; ++s) acc[oc][s] = (f32x4){0.f, 0.f, 0.f, 0.f};

    for (int ch = 0; ch < NCH; ++ch) {
#pragma unroll
        for (int it = 0; it < 7; ++it) {
            int u = tid + it * 256;
            if (u < 1728) {
                int r = u / 288;
                int rem = u - r * 288;
                int px = rem >> 2, c8 = rem & 3;
                int yin = y0 - 1 + r;
                int gx  = x0 - 4 + px;
                bf16x8 v = {0,0,0,0,0,0,0,0};
                if (yin >= 0 && yin < HH && gx >= 0 && gx < WW)
                    v = *(const bf16x8*)(in + (((size_t)(b * NCH + ch) * HH + yin) * WW + gx) * 32 + c8 * 8);
                *(bf16x8*)&sx[(r * 72 + px) * 32 + ((c8 ^ ((px >> 1) & 3)) << 3)] = v;
            }
        }
#pragma unroll
        for (int it = 0; it < 7; ++it) {
            int u = tid + it * 256;
            if (u < WGR) {
                int tap = u / (4 * COUT_TILE);
                int rem = u - tap * 4 * COUT_TILE;
                int kgi = rem / COUT_TILE;
                int row = rem - kgi * COUT_TILE;
                bf16x8 v = *(const bf16x8*)(wb
                    + ((size_t)((tap * NCH + ch) * coutFull) + ocT + row) * 32 + kgi * 8);
                *(bf16x8*)&sw[((tap * 4 + kgi) * COUT_TILE + row) * 8] = v;
            }
        }
        __syncthreads();
#pragma unroll
        for (int ky = 0; ky < 3; ++ky) {
#pragma unroll
            for (int kx = 0; kx < 3; ++kx) {
                const int r = wv + ky;
                const int tap = ky * 3 + kx;
                bf16x8 bf[4];
#pragma unroll
                for (int s = 0; s < 4; ++s) {
                    int p = s * 16 + l15 + kx + 3;
                    bf[s] = *(const bf16x8*)&sx[(r * 72 + p) * 32 + ((kg ^ ((p >> 1) & 3)) << 3)];
                }
#pragma unroll
                for (int oc = 0; oc < NOC; ++oc) {
                    bf16x8 a = *(const bf16x8*)&sw[((tap * 4 + kg) * COUT_TILE + oc * 16 + l15) * 8];
#pragma unroll
                    for (int s = 0; s < 4; ++s)
                        acc[oc][s] = __builtin_amdgcn_mfma_f32_16x16x32_bf16(a, bf[s], acc[oc][s], 0, 0, 0);
                }
            }
        }
        __syncthreads();
    }
    const int y = y0 + wv;
    if (EPI == 1) {
        float* out = (float*)outp;
#pragma unroll
        for (int oc = 0; oc < NOC; ++oc)
#pragma unroll
            for (int s = 0; s < 4; ++s) {
                int xo = x0 + s * 16 + l15;
#pragma unroll
                for (int j = 0; j < 4; ++j) {
                    int oL = ocT + oc * 16 + kg * 4 + j;
                    float rv = acc[oc][s][j] + bias[oL];
                    if (RELU) rv = fmaxf(rv, 0.f);
                    out[((size_t)(b * cTot + ocBase + oL) * HH + y) * WW + xo] = rv;
                }
            }
    } else if (EPI == 2) {
        unsigned short* out = (unsigned short*)outp;
#pragma unroll
        for (int oc = 0; oc < NOC; ++oc)
#pragma unroll
            for (int s = 0; s < 4; ++s) {
                int xo = x0 + s * 16 + l15;
#pragma unroll
                for (int j = 0; j < 4; ++j) {
                    int oL = ocT + oc * 16 + kg * 4 + j;
                    float rv = acc[oc][s][j] + bias[oL];
                    if (RELU) rv = fmaxf(rv, 0.f);
                    out[((size_t)(b * cTot + ocBase + oL) * HH + y) * WW + xo] = f2bf(rv);
                }
            }
    } else {
        unsigned short* out = (unsigned short*)outp;
#pragma unroll
        for (int oc = 0; oc < NOC; ++oc) {
            int oL = ocT + oc * 16 + kg * 4;
            int o0 = ocBase + oL;
#pragma unroll
            for (int s = 0; s < 4; ++s) {
                int xo = x0 + s * 16 + l15;
                ushort4 u;
                float r0 = acc[oc][s][0] + bias[oL + 0];
                float r1 = acc[oc][s][1] + bias[oL + 1];
                float r2 = acc[oc][s][2] + bias[oL + 2];
                float r3 = acc[oc][s][3] + bias[oL + 3];
                if (RELU) { r0 = fmaxf(r0,0.f); r1 = fmaxf(r1,0.f); r2 = fmaxf(r2,0.f); r3 = fmaxf(r3,0.f); }
                u.x = f2bf(r0); u.y = f2bf(r1); u.z = f2bf(r2); u.w = f2bf(r3);
                *(ushort4*)(out + ((((size_t)(b * cTot + (o0 >> 5)) * HH + y) * WW + xo) * 32) + (o0 & 31)) = u;
            }
        }
    }
}

// ---------- deformable conv v7: cl8 ref layout ----------
__global__ __launch_bounds__(512, 4) void deform_v7(
    const unsigned short* __restrict__ xb8, const unsigned short* __restrict__ offb,
    const unsigned short* __restrict__ wdefb2, const float* __restrict__ bias,
    unsigned short* __restrict__ cat)
{
    __shared__ __align__(16) unsigned short smp[64 * 584];
    const int tid = threadIdx.x;
    const int b = blockIdx.z;
    int flat = blockIdx.x;
    int nf = (flat & 7) * 72 + (flat >> 3);
    const int pixbase = nf * 64;

    const int px = tid & 63, g = tid >> 6;
    const int pix = pixbase + px;
    const int y = pix / WW, x = pix - y * WW;

    const char* xgb = (const char*)(xb8 + (size_t)(b * 8 + g) * HWSZ * 8);
    const unsigned short* ob = offb + ((size_t)(b * 144 + g * 18)) * HWSZ + pix;

    float dyv[9], dxv[9];
#pragma unroll
    for (int k = 0; k < 9; ++k) {
        dyv[k] = bf2f(ob[(size_t)(2 * k) * HWSZ]);
        dxv[k] = bf2f(ob[(size_t)(2 * k + 1) * HWSZ]);
    }

    auto calc = [&](int k, int vo[4], float w4[4]) {
        float pyf = (float)(y + k / 3 - 1) + dyv[k];
        float pxf = (float)(x + k % 3 - 1) + dxv[k];
        float fy = floorf(pyf), fx = floorf(pxf);
        float wy = pyf - fy, wx = pxf - fx;
        int iy = (int)fy, ix = (int)fx;
        float w00 = (1.f - wy) * (1.f - wx), w01 = (1.f - wy) * wx;
        float w10 = wy * (1.f - wx),         w11 = wy * wx;
        bool y0v = (iy >= 0) && (iy < HH);
        bool y1v = (iy + 1 >= 0) && (iy + 1 < HH);
        bool x0v = (ix >= 0) && (ix < WW);
        bool x1v = (ix + 1 >= 0) && (ix + 1 < WW);
        if (!(y0v && x0v)) w00 = 0.f;
        if (!(y0v && x1v)) w01 = 0.f;
        if (!(y1v && x0v)) w10 = 0.f;
        if (!(y1v && x1v)) w11 = 0.f;
        int cy0 = min(max(iy, 0), HH - 1), cy1 = min(max(iy + 1, 0), HH - 1);
        int cx0 = min(max(ix, 0), WW - 1), cx1 = min(max(ix + 1, 0), WW - 1);
        vo[0] = (cy0 * WW + cx0) * 16;
        vo[1] = (cy0 * WW + cx1) * 16;
        vo[2] = (cy1 * WW + cx0) * 16;
        vo[3] = (cy1 * WW + cx1) * 16;
        w4[0] = w00; w4[1] = w01; w4[2] = w10; w4[3] = w11;
    };

    float wr[3][4];
    bf16x8 pf[2][4];
    {
        int vo[4]; calc(0, vo, wr[0]);
#pragma unroll
        for (int j = 0; j < 4; ++j) pf[0][j] = *(const bf16x8*)(xgb + vo[j]);
    }
    {
        int vo[4]; calc(1, vo, wr[1]);
#pragma unroll
        for (int j = 0; j < 4; ++j) pf[1][j] = *(const bf16x8*)(xgb + vo[j]);
    }
    unsigned short* so = smp + px * 584 + g * 8;
#pragma unroll
    for (int k = 0; k < 9; ++k) {
        bf16x8 nx0, nx1, nx2, nx3;
        if (k + 2 < 9) {
            int vo[4]; calc(k + 2, vo, wr[(k + 2) % 3]);
            nx0 = *(const bf16x8*)(xgb + vo[0]);
            nx1 = *(const bf16x8*)(xgb + vo[1]);
            nx2 = *(const bf16x8*)(xgb + vo[2]);
            nx3 = *(const bf16x8*)(xgb + vo[3]);
        }
        __builtin_amdgcn_sched_barrier(0);
        bf16x8 ov;
#pragma unroll
        for (int cc = 0; cc < 8; ++cc) {
            float s = bf2f((unsigned short)pf[k & 1][0][cc]) * wr[k % 3][0]
                    + bf2f((unsigned short)pf[k & 1][1][cc]) * wr[k % 3][1]
                    + bf2f((unsigned short)pf[k & 1][2][cc]) * wr[k % 3][2]
                    + bf2f((unsigned short)pf[k & 1][3][cc]) * wr[k % 3][3];
            ov[cc] = (short)f2bf(s);
        }
        *(bf16x8*)(so + k * 64) = ov;
        if (k + 2 < 9) { pf[k & 1][0] = nx0; pf[k & 1][1] = nx1; pf[k & 1][2] = nx2; pf[k & 1][3] = nx3; }
    }
    __syncthreads();
    const int wv = tid >> 6;
    const int lane = tid & 63, l15 = lane & 15, kg = lane >> 4;
    const int oc = wv >> 1, sp = (wv & 1) * 2;
    f32x4 acc0 = (f32x4){0.f, 0.f, 0.f, 0.f};
    f32x4 acc1 = (f32x4){0.f, 0.f, 0.f, 0.f};
    const unsigned short* arow = wdefb2 + ((size_t)(oc * 16 + l15)) * 32 + kg * 8;
#pragma unroll
    for (int ch = 0; ch < 18; ++ch) {
        bf16x8 b0 = *(const bf16x8*)&smp[(sp * 16 + l15) * 584 + ch * 32 + kg * 8];
        bf16x8 b1 = *(const bf16x8*)&smp[((sp + 1) * 16 + l15) * 584 + ch * 32 + kg * 8];
        bf16x8 a = *(const bf16x8*)(arow + (size_t)ch * 64 * 32);
        acc0 = __builtin_amdgcn_mfma_f32_16x16x32_bf16(a, b0, acc0, 0, 0, 0);
        acc1 = __builtin_amdgcn_mfma_f32_16x16x32_bf16(a, b1, acc1, 0, 0, 0);
    }
    const int o0 = oc * 16 + kg * 4;
#pragma unroll
    for (int s = 0; s < 2; ++s) {
        const f32x4& av = s ? acc1 : acc0;
        int pxo = pixbase + (sp + s) * 16 + l15;
        int yo = pxo / WW, xo = pxo - yo * WW;
        ushort4 u;
        u.x = f2bf(fmaxf(av[0] + bias[o0 + 0], 0.f));
        u.y = f2bf(fmaxf(av[1] + bias[o0 + 1], 0.f));
        u.z = f2bf(fmaxf(av[2] + bias[o0 + 2], 0.f));
        u.w = f2bf(fmaxf(av[3] + bias[o0 + 3], 0.f));
        *(ushort4*)(cat + ((((size_t)(b * 4 + (o0 >> 5)) * HH + yo) * WW + xo) * 32) + (o0 & 31)) = u;
    }
}

// ---------------- global average pool over bf16 cl32 x2 ----------------
// grid = BB*2 (one block per (b, chunk-of-32ch)); thread t reads granule
// (pixgroup = t>>2, c8 = t&3) -> first iteration reads 256 contiguous granules.
__global__ __launch_bounds__(256) void pool_cl32(
    const unsigned short* __restrict__ x2b, float* __restrict__ gout)
{
    __shared__ float red[256][8];
    const int blk = blockIdx.x;                 // b*2 + chunk
    const unsigned short* base = x2b + (size_t)blk * HWSZ * 32;
    const int tid = threadIdx.x;
    const int c8 = tid & 3, pg = tid >> 2;
    float acc[8];
#pragma unroll
    for (int j = 0; j < 8; ++j) acc[j] = 0.f;
    for (int p = pg; p < HWSZ; p += 64) {
        bf16x8 v = *(const bf16x8*)(base + (size_t)p * 32 + c8 * 8);
#pragma unroll
        for (int j = 0; j < 8; ++j) acc[j] += bf2f((unsigned short)v[j]);
    }
#pragma unroll
    for (int j = 0; j < 8; ++j) red[tid][j] = acc[j];
    __syncthreads();
    if (tid < 32) {
        float s = 0.f;
        for (int j = 0; j < 64; ++j) s += red[(j << 2) | (tid >> 3)][tid & 7];
        gout[(blk >> 1) * 64 + (blk & 1) * 32 + tid] = s * (1.f / (float)HWSZ);
    }
}

// ---------------- SE MLP ----------------
__global__ __launch_bounds__(256) void se_kernel(
    const float* __restrict__ g, const float* __restrict__ w1, const float* __restrict__ b1,
    const float* __restrict__ w2, const float* __restrict__ b2, float* __restrict__ a)
{
    __shared__ float sg[BB * 64];
    __shared__ float sh[BB * 32];
    int tid = threadIdx.x;
    sg[tid] = g[tid];
    __syncthreads();
    if (tid < BB * 32) {
        int b = tid / 32, h = tid % 32;
        float s = b1[h];
        for (int c = 0; c < 64; ++c) s += sg[b * 64 + c] * w1[h * 64 + c];
        sh[b * 32 + h] = fmaxf(s, 0.f);
    }
    __syncthreads();
    {
        int b = tid / 64, o = tid % 64;
        float s = b2[o];
        for (int h = 0; h < 32; ++h) s += sh[b * 32 + h] * w2[o * 32 + h];
        a[tid] = 1.f / (1.f + expf(-s));
    }
}

// ---------------- final: out = def + x2*a (both bf16 cl32 in, f32 out, no read of out) ----------------
__global__ __launch_bounds__(256) void final_v3(
    float* __restrict__ out, const unsigned short* __restrict__ catb,
    const unsigned short* __restrict__ x2b, const float* __restrict__ a)
{
    const int VPC = HWSZ / 4;
    int v = blockIdx.x * 256 + threadIdx.x;
    int bc = v / VPC, within = v - bc * VPC;
    int b = bc >> 6, c = bc & 63;
    float av = a[bc];
    int pix = within * 4;
    int y = pix / WW, x = pix - y * WW;
    const unsigned short* dbase = catb
        + (((size_t)(b * 4 + (c >> 5)) * HH + y) * WW + x) * 32 + (c & 31);
    const unsigned short* xbase = x2b
        + (((size_t)(b * 2 + (c >> 5)) * HH + y) * WW + x) * 32 + (c & 31);
    float4 r;
    r.x = bf2f(dbase[0])  + bf2f(xbase[0])  * av;
    r.y = bf2f(dbase[32]) + bf2f(xbase[32]) * av;
    r.z = bf2f(dbase[64]) + bf2f(xbase[64]) * av;
    r.w = bf2f(dbase[96]) + bf2f(xbase[96]) * av;
    reinterpret_cast<float4*>(out)[v] = r;
}

extern "C" void kernel_launch(void* const* d_in, const int* in_sizes, int n_in,
                              void* d_out, int out_size, void* d_ws, size_t ws_size,
                              hipStream_t stream) {
    const float* mv     = (const float*)d_in[0];
    const float* ref    = (const float*)d_in[1];
    const float* head_w = (const float*)d_in[2];
    const float* head_b = (const float*)d_in[3];
    const float* dcn_w  = (const float*)d_in[4];
    const float* dcn_b  = (const float*)d_in[5];
    const float* c1w1   = (const float*)d_in[6];
    const float* c1b1   = (const float*)d_in[7];
    const float* c1w2   = (const float*)d_in[8];
    const float* c1b2   = (const float*)d_in[9];
    const float* aux_w  = (const float*)d_in[10];
    const float* aux_b  = (const float*)d_in[11];
    const float* fw1    = (const float*)d_in[12];
    const float* fb1    = (const float*)d_in[13];
    const float* fw2    = (const float*)d_in[14];
    const float* fb2    = (const float*)d_in[15];
    const float* se_w1  = (const float*)d_in[16];
    const float* se_b1  = (const float*)d_in[17];
    const float* se_w2  = (const float*)d_in[18];
    const float* se_b2  = (const float*)d_in[19];
    float* out = (float*)d_out;

    float* ws = (float*)d_ws;
    unsigned short* offb     = (unsigned short*)ws;                  // 21,233,664 sh (bf16 offsets)
    unsigned short* mvb      = (unsigned short*)(ws + 21233664);     // 18,874,368 sh
    unsigned short* refb     = (unsigned short*)(ws + 30670848);     //  9,437,184 sh
    unsigned short* catb     = (unsigned short*)(ws + 35389440);     // 18,874,368 sh
    unsigned short* r2b      = (unsigned short*)(ws + 44826624);     // 18,874,368 sh
    unsigned short* wdefb2   = (unsigned short*)(ws + 54263808);     //     36,864 sh
    unsigned short* wbb      = (unsigned short*)(ws + 54282240);     //    571,392 sh
    unsigned short* refb8    = wbb + 571392;                         //  9,437,184 sh (cl8 ref)
    float* gbuf              = (float*)(refb8 + 9437184 + 16);
    float* abuf              = gbuf + 256;
    unsigned short* t1b      = (unsigned short*)ws;                  // reuse off region after deform
    unsigned short* x2b      = mvb;                                  // reuse mv region after head conv

    unsigned short* wb_head = wbb;                    // 144*128*9
    unsigned short* wb_c1w1 = wb_head + 165888;       // 128*64*9
    unsigned short* wb_c1w2 = wb_c1w1 + 73728;        // 128*128*9
    unsigned short* wb_aux  = wb_c1w2 + 147456;       // 64*128*9
    unsigned short* wb_fw1  = wb_aux  + 73728;        // 64*128*9
    unsigned short* wb_fw2  = wb_fw1  + 73728;        // 64*64*9

    prep_all<<<2376, 256, 0, stream>>>(head_w, c1w1, c1w2, aux_w, fw1, fw2, dcn_w,
                                       wb_head, wb_c1w1, wb_c1w2, wb_aux, wb_fw1, wb_fw2, wdefb2);
    transpose_all<<<dim3(3, 192, 24), 256, 0, stream>>>(mv, ref, mvb, refb, refb8);

    // 1. offsets = conv(mv)                    128 -> 144   (bf16 NCHW, 3 oc-tiles of 48)
    conv3x3_v10<128, 48, false, 2><<<1728, 256, 0, stream>>>(
        mvb, wb_head, head_b, offb, 144, 0, 3, 144, 216);
    // 2. def_feat = relu(deform(ref cl8, offsets)) -> catb chunks 0-1
    deform_v7<<<dim3(576, 1, BB), 512, 0, stream>>>(refb8, offb, wdefb2, dcn_b, catb);
    // 3. t1 = relu(conv(ref, c1w1))            64 -> 128    (4 oc-tiles of 32)
    conv3x3_v10<64, 32, true, 0><<<2304, 256, 0, stream>>>(
        refb, wb_c1w1, c1b1, t1b, 4, 0, 4, 128, 288);
    // 4. aux_in = relu(conv(t1, c1w2))         128 -> 128   (4 oc-tiles of 32)
    conv3x3_v10<128, 32, true, 0><<<2304, 256, 0, stream>>>(
        t1b, wb_c1w2, c1b2, r2b, 4, 0, 4, 128, 288);
    // 5. aux = relu(conv(aux_in, aux_w))       128 -> 64    -> catb chunks 2-3 (2 tiles of 32)
    conv3x3_v10<128, 32, true, 0><<<1152, 256, 0, stream>>>(
        r2b, wb_aux, aux_b, catb, 4, 64, 2, 64, 144);
    // 6. x1 = relu(conv(cat, fw1))             128 -> 64    (2 tiles of 32)
    conv3x3_v10<128, 32, true, 0><<<1152, 256, 0, stream>>>(
        catb, wb_fw1, fb1, r2b, 2, 0, 2, 64, 144);
    // 7. x2 = conv(x1, fw2)                    64 -> 64     -> x2b (bf16 cl32, reuses mv region)
    conv3x3_v10<64, 32, false, 0><<<1152, 256, 0, stream>>>(
        r2b, wb_fw2, fb2, x2b, 2, 0, 2, 64, 144);
    // 8-10. pool (cl32), SE, final = def + x2*a
    pool_cl32<<<BB * 2, 256, 0, stream>>>(x2b, gbuf);
    se_kernel<<<1, 256, 0, stream>>>(gbuf, se_w1, se_b1, se_w2, se_b2, abuf);
    final_v3<<<9216, 256, 0, stream>>>(out, catb, x2b, abuf);
}

// Round 21
// 445.419 us; speedup vs baseline: 1.3504x; 1.3504x over previous
//
#include <hip/hip_runtime.h>
#include <math.h>

#define HH 192
#define WW 192
#define HWSZ (HH*WW)
#define BB 4

typedef __attribute__((ext_vector_type(8))) short bf16x8;
typedef __attribute__((ext_vector_type(4))) float f32x4;

__device__ __forceinline__ unsigned short f2bf(float f) {
    unsigned int u = __float_as_uint(f);
    u = (u + 0x7FFFu + ((u >> 16) & 1u)) >> 16;
    return (unsigned short)u;
}
__device__ __forceinline__ float bf2f(unsigned short s) {
    return __uint_as_float(((unsigned int)s) << 16);
}

// ---------- merged weight prep: 6 convs + dcn in ONE launch ----------
__global__ void prep_all(
    const float* __restrict__ head_w, const float* __restrict__ c1w1,
    const float* __restrict__ c1w2,   const float* __restrict__ aux_w,
    const float* __restrict__ fw1,    const float* __restrict__ fw2,
    const float* __restrict__ dcn_w,
    unsigned short* __restrict__ wb_head, unsigned short* __restrict__ wb_c1w1,
    unsigned short* __restrict__ wb_c1w2, unsigned short* __restrict__ wb_aux,
    unsigned short* __restrict__ wb_fw1,  unsigned short* __restrict__ wb_fw2,
    unsigned short* __restrict__ wdefb2)
{
    int idx = blockIdx.x * 256 + threadIdx.x;
    const float* w; unsigned short* wb; int cout, cin;
    if (idx < 165888)                 { w = head_w; wb = wb_head; cout = 144; cin = 128; }
    else if ((idx -= 165888) < 73728) { w = c1w1;   wb = wb_c1w1; cout = 128; cin = 64;  }
    else if ((idx -= 73728) < 147456) { w = c1w2;   wb = wb_c1w2; cout = 128; cin = 128; }
    else if ((idx -= 147456) < 73728) { w = aux_w;  wb = wb_aux;  cout = 64;  cin = 128; }
    else if ((idx -= 73728) < 73728)  { w = fw1;    wb = wb_fw1;  cout = 64;  cin = 128; }
    else if ((idx -= 73728) < 36864)  { w = fw2;    wb = wb_fw2;  cout = 64;  cin = 64;  }
    else if ((idx -= 36864) < 36864) {
        int o = idx / 576, rem = idx % 576;
        int c = rem / 9, k = rem - c * 9;
        int K = k * 64 + c;
        wdefb2[((size_t)((K >> 5) * 64 + o)) * 32 + (K & 31)] = f2bf(dcn_w[idx]);
        return;
    } else return;
    int o = idx / (cin * 9);
    int rem = idx - o * cin * 9;
    int c = rem / 9;
    int t = rem - c * 9;
    int nch = cin >> 5;
    wb[((t * nch + (c >> 5)) * cout + o) * 32 + (c & 31)] = f2bf(w[idx]);
}

// ---------- transpose f32 NCHW -> bf16 cl32 (mv+ref) AND cl8 (ref only) ----------
__global__ __launch_bounds__(256) void transpose_all(
    const float* __restrict__ mv, const float* __restrict__ ref,
    unsigned short* __restrict__ mvb, unsigned short* __restrict__ refb,
    unsigned short* __restrict__ refb8)
{
    __shared__ float tile[32][68];
    const int tid = threadIdx.x;
    int bz = blockIdx.z;
    const float* in; unsigned short* outb;
    bool isRef = (bz >= 16);
    int bzr = isRef ? bz - 16 : bz;
    if (isRef) { in = ref; outb = refb; }
    else       { in = mv;  outb = mvb;  }
    const int y = blockIdx.y;
    const int x0 = blockIdx.x * 64;
#pragma unroll
    for (int it = 0; it < 2; ++it) {
        int u = tid + it * 256;
        int c = u >> 4, q = u & 15;
        float4 v = *(const float4*)(in + (((size_t)bzr * 32 + c) * HH + y) * WW + x0 + q * 4);
        *(float4*)&tile[c][q * 4] = v;
    }
    __syncthreads();
    const int pxl = tid >> 2, c8 = tid & 3;
    bf16x8 ov;
#pragma unroll
    for (int j = 0; j < 8; ++j) ov[j] = (short)f2bf(tile[c8 * 8 + j][pxl]);
    *(bf16x8*)(outb + (((size_t)bzr * HH + y) * WW + x0 + pxl) * 32 + c8 * 8) = ov;
    if (isRef) {
        *(bf16x8*)(refb8 + ((size_t)(bzr * 4 + c8) * HWSZ + (size_t)y * WW + x0 + pxl) * 8) = ov;
    }
}

// ---------- 3x3 conv v10: input AND weights staged in LDS per chunk ----------
template<int CIN, int COUT_TILE, bool RELU, int EPI>
__global__ __launch_bounds__(256, 3) void conv3x3_v10(
    const unsigned short* __restrict__ in, const unsigned short* __restrict__ wb,
    const float* __restrict__ bias, void* __restrict__ outp,
    int cTot, int ocBase, int nOc, int coutFull, int nPerXcd)
{
    constexpr int NCH = CIN / 32;
    constexpr int NOC = COUT_TILE / 16;
    constexpr int WGR = 36 * COUT_TILE;
    __shared__ __align__(16) unsigned short sx[6 * 72 * 32];
    __shared__ __align__(16) unsigned short sw[288 * COUT_TILE];

    const int tid = threadIdx.x;
    const int d = blockIdx.x;
    const int w = (d & 7) * nPerXcd + (d >> 3);
    const int ocT = (w % nOc) * COUT_TILE;
    int t = w / nOc;
    const int x0 = (t % 3) * 64; t /= 3;
    const int y0 = (t % 48) * 4;
    const int b  = t / 48;
    const int wv = tid >> 6, lane = tid & 63;
    const int l15 = lane & 15, kg = lane >> 4;

    f32x4 acc[NOC][4];
#pragma unroll
    for (int oc = 0; oc < NOC; ++oc)
#pragma unroll
        for (int s = 0; s < 4; ++s) acc[oc][s] = (f32x4){0.f, 0.f, 0.f, 0.f};

    for (int ch = 0; ch < NCH; ++ch) {
#pragma unroll
        for (int it = 0; it < 7; ++it) {
            int u = tid + it * 256;
            if (u < 1728) {
                int r = u / 288;
                int rem = u - r * 288;
                int px = rem >> 2, c8 = rem & 3;
                int yin = y0 - 1 + r;
                int gx  = x0 - 4 + px;
                bf16x8 v = {0,0,0,0,0,0,0,0};
                if (yin >= 0 && yin < HH && gx >= 0 && gx < WW)
                    v = *(const bf16x8*)(in + (((size_t)(b * NCH + ch) * HH + yin) * WW + gx) * 32 + c8 * 8);
                *(bf16x8*)&sx[(r * 72 + px) * 32 + ((c8 ^ ((px >> 1) & 3)) << 3)] = v;
            }
        }
#pragma unroll
        for (int it = 0; it < 7; ++it) {
            int u = tid + it * 256;
            if (u < WGR) {
                int tap = u / (4 * COUT_TILE);
                int rem = u - tap * 4 * COUT_TILE;
                int kgi = rem / COUT_TILE;
                int row = rem - kgi * COUT_TILE;
                bf16x8 v = *(const bf16x8*)(wb
                    + ((size_t)((tap * NCH + ch) * coutFull) + ocT + row) * 32 + kgi * 8);
                *(bf16x8*)&sw[((tap * 4 + kgi) * COUT_TILE + row) * 8] = v;
            }
        }
        __syncthreads();
#pragma unroll
        for (int ky = 0; ky < 3; ++ky) {
#pragma unroll
            for (int kx = 0; kx < 3; ++kx) {
                const int r = wv + ky;
                const int tap = ky * 3 + kx;
                bf16x8 bf[4];
#pragma unroll
                for (int s = 0; s < 4; ++s) {
                    int p = s * 16 + l15 + kx + 3;
                    bf[s] = *(const bf16x8*)&sx[(r * 72 + p) * 32 + ((kg ^ ((p >> 1) & 3)) << 3)];
                }
#pragma unroll
                for (int oc = 0; oc < NOC; ++oc) {
                    bf16x8 a = *(const bf16x8*)&sw[((tap * 4 + kg) * COUT_TILE + oc * 16 + l15) * 8];
#pragma unroll
                    for (int s = 0; s < 4; ++s)
                        acc[oc][s] = __builtin_amdgcn_mfma_f32_16x16x32_bf16(a, bf[s], acc[oc][s], 0, 0, 0);
                }
            }
        }
        __syncthreads();
    }
    const int y = y0 + wv;
    if (EPI == 1) {
        float* out = (float*)outp;
#pragma unroll
        for (int oc = 0; oc < NOC; ++oc)
#pragma unroll
            for (int s = 0; s < 4; ++s) {
                int xo = x0 + s * 16 + l15;
#pragma unroll
                for (int j = 0; j < 4; ++j) {
                    int oL = ocT + oc * 16 + kg * 4 + j;
                    float rv = acc[oc][s][j] + bias[oL];
                    if (RELU) rv = fmaxf(rv, 0.f);
                    out[((size_t)(b * cTot + ocBase + oL) * HH + y) * WW + xo] = rv;
                }
            }
    } else if (EPI == 2) {
        unsigned short* out = (unsigned short*)outp;
#pragma unroll
        for (int oc = 0; oc < NOC; ++oc)
#pragma unroll
            for (int s = 0; s < 4; ++s) {
                int xo = x0 + s * 16 + l15;
#pragma unroll
                for (int j = 0; j < 4; ++j) {
                    int oL = ocT + oc * 16 + kg * 4 + j;
                    float rv = acc[oc][s][j] + bias[oL];
                    if (RELU) rv = fmaxf(rv, 0.f);
                    out[((size_t)(b * cTot + ocBase + oL) * HH + y) * WW + xo] = f2bf(rv);
                }
            }
    } else {
        unsigned short* out = (unsigned short*)outp;
#pragma unroll
        for (int oc = 0; oc < NOC; ++oc) {
            int oL = ocT + oc * 16 + kg * 4;
            int o0 = ocBase + oL;
#pragma unroll
            for (int s = 0; s < 4; ++s) {
                int xo = x0 + s * 16 + l15;
                ushort4 u;
                float r0 = acc[oc][s][0] + bias[oL + 0];
                float r1 = acc[oc][s][1] + bias[oL + 1];
                float r2 = acc[oc][s][2] + bias[oL + 2];
                float r3 = acc[oc][s][3] + bias[oL + 3];
                if (RELU) { r0 = fmaxf(r0,0.f); r1 = fmaxf(r1,0.f); r2 = fmaxf(r2,0.f); r3 = fmaxf(r3,0.f); }
                u.x = f2bf(r0); u.y = f2bf(r1); u.z = f2bf(r2); u.w = f2bf(r3);
                *(ushort4*)(out + ((((size_t)(b * cTot + (o0 >> 5)) * HH + y) * WW + xo) * 32) + (o0 & 31)) = u;
            }
        }
    }
}

// ---------- deformable conv v7: cl8 ref layout ----------
__global__ __launch_bounds__(512, 4) void deform_v7(
    const unsigned short* __restrict__ xb8, const unsigned short* __restrict__ offb,
    const unsigned short* __restrict__ wdefb2, const float* __restrict__ bias,
    unsigned short* __restrict__ cat)
{
    __shared__ __align__(16) unsigned short smp[64 * 584];
    const int tid = threadIdx.x;
    const int b = blockIdx.z;
    int flat = blockIdx.x;
    int nf = (flat & 7) * 72 + (flat >> 3);
    const int pixbase = nf * 64;

    const int px = tid & 63, g = tid >> 6;
    const int pix = pixbase + px;
    const int y = pix / WW, x = pix - y * WW;

    const char* xgb = (const char*)(xb8 + (size_t)(b * 8 + g) * HWSZ * 8);
    const unsigned short* ob = offb + ((size_t)(b * 144 + g * 18)) * HWSZ + pix;

    float dyv[9], dxv[9];
#pragma unroll
    for (int k = 0; k < 9; ++k) {
        dyv[k] = bf2f(ob[(size_t)(2 * k) * HWSZ]);
        dxv[k] = bf2f(ob[(size_t)(2 * k + 1) * HWSZ]);
    }

    auto calc = [&](int k, int vo[4], float w4[4]) {
        float pyf = (float)(y + k / 3 - 1) + dyv[k];
        float pxf = (float)(x + k % 3 - 1) + dxv[k];
        float fy = floorf(pyf), fx = floorf(pxf);
        float wy = pyf - fy, wx = pxf - fx;
        int iy = (int)fy, ix = (int)fx;
        float w00 = (1.f - wy) * (1.f - wx), w01 = (1.f - wy) * wx;
        float w10 = wy * (1.f - wx),         w11 = wy * wx;
        bool y0v = (iy >= 0) && (iy < HH);
        bool y1v = (iy + 1 >= 0) && (iy + 1 < HH);
        bool x0v = (ix >= 0) && (ix < WW);
        bool x1v = (ix + 1 >= 0) && (ix + 1 < WW);
        if (!(y0v && x0v)) w00 = 0.f;
        if (!(y0v && x1v)) w01 = 0.f;
        if (!(y1v && x0v)) w10 = 0.f;
        if (!(y1v && x1v)) w11 = 0.f;
        int cy0 = min(max(iy, 0), HH - 1), cy1 = min(max(iy + 1, 0), HH - 1);
        int cx0 = min(max(ix, 0), WW - 1), cx1 = min(max(ix + 1, 0), WW - 1);
        vo[0] = (cy0 * WW + cx0) * 16;
        vo[1] = (cy0 * WW + cx1) * 16;
        vo[2] = (cy1 * WW + cx0) * 16;
        vo[3] = (cy1 * WW + cx1) * 16;
        w4[0] = w00; w4[1] = w01; w4[2] = w10; w4[3] = w11;
    };

    float wr[3][4];
    bf16x8 pf[2][4];
    {
        int vo[4]; calc(0, vo, wr[0]);
#pragma unroll
        for (int j = 0; j < 4; ++j) pf[0][j] = *(const bf16x8*)(xgb + vo[j]);
    }
    {
        int vo[4]; calc(1, vo, wr[1]);
#pragma unroll
        for (int j = 0; j < 4; ++j) pf[1][j] = *(const bf16x8*)(xgb + vo[j]);
    }
    unsigned short* so = smp + px * 584 + g * 8;
#pragma unroll
    for (int k = 0; k < 9; ++k) {
        bf16x8 nx0, nx1, nx2, nx3;
        if (k + 2 < 9) {
            int vo[4]; calc(k + 2, vo, wr[(k + 2) % 3]);
            nx0 = *(const bf16x8*)(xgb + vo[0]);
            nx1 = *(const bf16x8*)(xgb + vo[1]);
            nx2 = *(const bf16x8*)(xgb + vo[2]);
            nx3 = *(const bf16x8*)(xgb + vo[3]);
        }
        __builtin_amdgcn_sched_barrier(0);
        bf16x8 ov;
#pragma unroll
        for (int cc = 0; cc < 8; ++cc) {
            float s = bf2f((unsigned short)pf[k & 1][0][cc]) * wr[k % 3][0]
                    + bf2f((unsigned short)pf[k & 1][1][cc]) * wr[k % 3][1]
                    + bf2f((unsigned short)pf[k & 1][2][cc]) * wr[k % 3][2]
                    + bf2f((unsigned short)pf[k & 1][3][cc]) * wr[k % 3][3];
            ov[cc] = (short)f2bf(s);
        }
        *(bf16x8*)(so + k * 64) = ov;
        if (k + 2 < 9) { pf[k & 1][0] = nx0; pf[k & 1][1] = nx1; pf[k & 1][2] = nx2; pf[k & 1][3] = nx3; }
    }
    __syncthreads();
    const int wv = tid >> 6;
    const int lane = tid & 63, l15 = lane & 15, kg = lane >> 4;
    const int oc = wv >> 1, sp = (wv & 1) * 2;
    f32x4 acc0 = (f32x4){0.f, 0.f, 0.f, 0.f};
    f32x4 acc1 = (f32x4){0.f, 0.f, 0.f, 0.f};
    const unsigned short* arow = wdefb2 + ((size_t)(oc * 16 + l15)) * 32 + kg * 8;
#pragma unroll
    for (int ch = 0; ch < 18; ++ch) {
        bf16x8 b0 = *(const bf16x8*)&smp[(sp * 16 + l15) * 584 + ch * 32 + kg * 8];
        bf16x8 b1 = *(const bf16x8*)&smp[((sp + 1) * 16 + l15) * 584 + ch * 32 + kg * 8];
        bf16x8 a = *(const bf16x8*)(arow + (size_t)ch * 64 * 32);
        acc0 = __builtin_amdgcn_mfma_f32_16x16x32_bf16(a, b0, acc0, 0, 0, 0);
        acc1 = __builtin_amdgcn_mfma_f32_16x16x32_bf16(a, b1, acc1, 0, 0, 0);
    }
    const int o0 = oc * 16 + kg * 4;
#pragma unroll
    for (int s = 0; s < 2; ++s) {
        const f32x4& av = s ? acc1 : acc0;
        int pxo = pixbase + (sp + s) * 16 + l15;
        int yo = pxo / WW, xo = pxo - yo * WW;
        ushort4 u;
        u.x = f2bf(fmaxf(av[0] + bias[o0 + 0], 0.f));
        u.y = f2bf(fmaxf(av[1] + bias[o0 + 1], 0.f));
        u.z = f2bf(fmaxf(av[2] + bias[o0 + 2], 0.f));
        u.w = f2bf(fmaxf(av[3] + bias[o0 + 3], 0.f));
        *(ushort4*)(cat + ((((size_t)(b * 4 + (o0 >> 5)) * HH + yo) * WW + xo) * 32) + (o0 & 31)) = u;
    }
}

// ---------------- pool stage 1: 256 blocks, partials to gp[256][32] ----------------
// blk = (b*2+chunk)*32 + part; each block reduces 1152 pixels of its chunk.
__global__ __launch_bounds__(256) void pool_cl32_v2(
    const unsigned short* __restrict__ x2b, float* __restrict__ gp)
{
    __shared__ float red[256][8];
    const int blk = blockIdx.x;
    const int b2 = blk >> 5, part = blk & 31;
    const unsigned short* base = x2b + (size_t)b2 * HWSZ * 32;
    const int tid = threadIdx.x;
    const int c8 = tid & 3, pg = tid >> 2;
    float acc[8];
#pragma unroll
    for (int j = 0; j < 8; ++j) acc[j] = 0.f;
    const int p0 = part * 1152;
    for (int p = p0 + pg; p < p0 + 1152; p += 64) {
        bf16x8 v = *(const bf16x8*)(base + (size_t)p * 32 + c8 * 8);
#pragma unroll
        for (int j = 0; j < 8; ++j) acc[j] += bf2f((unsigned short)v[j]);
    }
#pragma unroll
    for (int j = 0; j < 8; ++j) red[tid][j] = acc[j];
    __syncthreads();
    if (tid < 32) {
        // c = (tid>>3)*8 + (tid&7): sum over the 64 pixel-groups for this channel
        float s = 0.f;
        for (int j = 0; j < 64; ++j) s += red[(j << 2) | (tid >> 3)][tid & 7];
        gp[(size_t)blk * 32 + tid] = s;
    }
}

// ---------------- SE MLP (sums 32 partials per (b,chunk) channel) ----------------
__global__ __launch_bounds__(256) void se_kernel_v2(
    const float* __restrict__ gp, const float* __restrict__ w1, const float* __restrict__ b1,
    const float* __restrict__ w2, const float* __restrict__ b2, float* __restrict__ a)
{
    __shared__ float sg[BB * 64];
    __shared__ float sh[BB * 32];
    int tid = threadIdx.x;
    {
        int b = tid / 64, c = tid % 64;
        int b2 = b * 2 + (c >> 5), c32 = c & 31;
        float s = 0.f;
        for (int part = 0; part < 32; ++part)
            s += gp[((size_t)b2 * 32 + part) * 32 + c32];
        sg[tid] = s * (1.f / (float)HWSZ);
    }
    __syncthreads();
    if (tid < BB * 32) {
        int b = tid / 32, h = tid % 32;
        float s = b1[h];
        for (int c = 0; c < 64; ++c) s += sg[b * 64 + c] * w1[h * 64 + c];
        sh[b * 32 + h] = fmaxf(s, 0.f);
    }
    __syncthreads();
    {
        int b = tid / 64, o = tid % 64;
        float s = b2[o];
        for (int h = 0; h < 32; ++h) s += sh[b * 32 + h] * w2[o * 32 + h];
        a[tid] = 1.f / (1.f + expf(-s));
    }
}

// ---------------- final: out = def + x2*a (both bf16 cl32 in, f32 out) ----------------
__global__ __launch_bounds__(256) void final_v3(
    float* __restrict__ out, const unsigned short* __restrict__ catb,
    const unsigned short* __restrict__ x2b, const float* __restrict__ a)
{
    const int VPC = HWSZ / 4;
    int v = blockIdx.x * 256 + threadIdx.x;
    int bc = v / VPC, within = v - bc * VPC;
    int b = bc >> 6, c = bc & 63;
    float av = a[bc];
    int pix = within * 4;
    int y = pix / WW, x = pix - y * WW;
    const unsigned short* dbase = catb
        + (((size_t)(b * 4 + (c >> 5)) * HH + y) * WW + x) * 32 + (c & 31);
    const unsigned short* xbase = x2b
        + (((size_t)(b * 2 + (c >> 5)) * HH + y) * WW + x) * 32 + (c & 31);
    float4 r;
    r.x = bf2f(dbase[0])  + bf2f(xbase[0])  * av;
    r.y = bf2f(dbase[32]) + bf2f(xbase[32]) * av;
    r.z = bf2f(dbase[64]) + bf2f(xbase[64]) * av;
    r.w = bf2f(dbase[96]) + bf2f(xbase[96]) * av;
    reinterpret_cast<float4*>(out)[v] = r;
}

extern "C" void kernel_launch(void* const* d_in, const int* in_sizes, int n_in,
                              void* d_out, int out_size, void* d_ws, size_t ws_size,
                              hipStream_t stream) {
    const float* mv     = (const float*)d_in[0];
    const float* ref    = (const float*)d_in[1];
    const float* head_w = (const float*)d_in[2];
    const float* head_b = (const float*)d_in[3];
    const float* dcn_w  = (const float*)d_in[4];
    const float* dcn_b  = (const float*)d_in[5];
    const float* c1w1   = (const float*)d_in[6];
    const float* c1b1   = (const float*)d_in[7];
    const float* c1w2   = (const float*)d_in[8];
    const float* c1b2   = (const float*)d_in[9];
    const float* aux_w  = (const float*)d_in[10];
    const float* aux_b  = (const float*)d_in[11];
    const float* fw1    = (const float*)d_in[12];
    const float* fb1    = (const float*)d_in[13];
    const float* fw2    = (const float*)d_in[14];
    const float* fb2    = (const float*)d_in[15];
    const float* se_w1  = (const float*)d_in[16];
    const float* se_b1  = (const float*)d_in[17];
    const float* se_w2  = (const float*)d_in[18];
    const float* se_b2  = (const float*)d_in[19];
    float* out = (float*)d_out;

    float* ws = (float*)d_ws;
    unsigned short* offb     = (unsigned short*)ws;                  // 21,233,664 sh (bf16 offsets)
    unsigned short* mvb      = (unsigned short*)(ws + 21233664);     // 18,874,368 sh
    unsigned short* refb     = (unsigned short*)(ws + 30670848);     //  9,437,184 sh
    unsigned short* catb     = (unsigned short*)(ws + 35389440);     // 18,874,368 sh
    unsigned short* r2b      = (unsigned short*)(ws + 44826624);     // 18,874,368 sh
    unsigned short* wdefb2   = (unsigned short*)(ws + 54263808);     //     36,864 sh
    unsigned short* wbb      = (unsigned short*)(ws + 54282240);     //    571,392 sh
    unsigned short* refb8    = wbb + 571392;                         //  9,437,184 sh (cl8 ref)
    float* gp                = (float*)(refb8 + 9437184 + 16);       // 256*32 partials
    float* abuf              = gp + 8192;
    unsigned short* t1b      = (unsigned short*)ws;                  // reuse off region after deform
    unsigned short* x2b      = mvb;                                  // reuse mv region after head conv

    unsigned short* wb_head = wbb;                    // 144*128*9
    unsigned short* wb_c1w1 = wb_head + 165888;       // 128*64*9
    unsigned short* wb_c1w2 = wb_c1w1 + 73728;        // 128*128*9
    unsigned short* wb_aux  = wb_c1w2 + 147456;       // 64*128*9
    unsigned short* wb_fw1  = wb_aux  + 73728;        // 64*128*9
    unsigned short* wb_fw2  = wb_fw1  + 73728;        // 64*64*9

    prep_all<<<2376, 256, 0, stream>>>(head_w, c1w1, c1w2, aux_w, fw1, fw2, dcn_w,
                                       wb_head, wb_c1w1, wb_c1w2, wb_aux, wb_fw1, wb_fw2, wdefb2);
    transpose_all<<<dim3(3, 192, 24), 256, 0, stream>>>(mv, ref, mvb, refb, refb8);

    // 1. offsets = conv(mv)                    128 -> 144   (bf16 NCHW, 3 oc-tiles of 48)
    conv3x3_v10<128, 48, false, 2><<<1728, 256, 0, stream>>>(
        mvb, wb_head, head_b, offb, 144, 0, 3, 144, 216);
    // 2. def_feat = relu(deform(ref cl8, offsets)) -> catb chunks 0-1
    deform_v7<<<dim3(576, 1, BB), 512, 0, stream>>>(refb8, offb, wdefb2, dcn_b, catb);
    // 3. t1 = relu(conv(ref, c1w1))            64 -> 128    (4 oc-tiles of 32)
    conv3x3_v10<64, 32, true, 0><<<2304, 256, 0, stream>>>(
        refb, wb_c1w1, c1b1, t1b, 4, 0, 4, 128, 288);
    // 4. aux_in = relu(conv(t1, c1w2))         128 -> 128   (4 oc-tiles of 32)
    conv3x3_v10<128, 32, true, 0><<<2304, 256, 0, stream>>>(
        t1b, wb_c1w2, c1b2, r2b, 4, 0, 4, 128, 288);
    // 5. aux = relu(conv(aux_in, aux_w))       128 -> 64    -> catb chunks 2-3 (2 tiles of 32)
    conv3x3_v10<128, 32, true, 0><<<1152, 256, 0, stream>>>(
        r2b, wb_aux, aux_b, catb, 4, 64, 2, 64, 144);
    // 6. x1 = relu(conv(cat, fw1))             128 -> 64    (2 tiles of 32)
    conv3x3_v10<128, 32, true, 0><<<1152, 256, 0, stream>>>(
        catb, wb_fw1, fb1, r2b, 2, 0, 2, 64, 144);
    // 7. x2 = conv(x1, fw2)                    64 -> 64     -> x2b (bf16 cl32, reuses mv region)
    conv3x3_v10<64, 32, false, 0><<<1152, 256, 0, stream>>>(
        r2b, wb_fw2, fb2, x2b, 2, 0, 2, 64, 144);
    // 8-10. pool (256 blocks, partials), SE (+partial reduce), final = def + x2*a
    pool_cl32_v2<<<256, 256, 0, stream>>>(x2b, gp);
    se_kernel_v2<<<1, 256, 0, stream>>>(gp, se_w1, se_b1, se_w2, se_b2, abuf);
    final_v3<<<9216, 256, 0, stream>>>(out, catb, x2b, abuf);
}

// Round 22
// 433.368 us; speedup vs baseline: 1.3879x; 1.0278x over previous
//
#include <hip/hip_runtime.h>
#include <math.h>

#define HH 192
#define WW 192
#define HWSZ (HH*WW)
#define BB 4

typedef __attribute__((ext_vector_type(8))) short bf16x8;
typedef __attribute__((ext_vector_type(4))) float f32x4;

__device__ __forceinline__ unsigned short f2bf(float f) {
    unsigned int u = __float_as_uint(f);
    u = (u + 0x7FFFu + ((u >> 16) & 1u)) >> 16;
    return (unsigned short)u;
}
__device__ __forceinline__ float bf2f(unsigned short s) {
    return __uint_as_float(((unsigned int)s) << 16);
}

// ---------- merged weight prep: 6 convs + dcn in ONE launch ----------
__global__ void prep_all(
    const float* __restrict__ head_w, const float* __restrict__ c1w1,
    const float* __restrict__ c1w2,   const float* __restrict__ aux_w,
    const float* __restrict__ fw1,    const float* __restrict__ fw2,
    const float* __restrict__ dcn_w,
    unsigned short* __restrict__ wb_head, unsigned short* __restrict__ wb_c1w1,
    unsigned short* __restrict__ wb_c1w2, unsigned short* __restrict__ wb_aux,
    unsigned short* __restrict__ wb_fw1,  unsigned short* __restrict__ wb_fw2,
    unsigned short* __restrict__ wdefb2)
{
    int idx = blockIdx.x * 256 + threadIdx.x;
    const float* w; unsigned short* wb; int cout, cin;
    if (idx < 165888)                 { w = head_w; wb = wb_head; cout = 144; cin = 128; }
    else if ((idx -= 165888) < 73728) { w = c1w1;   wb = wb_c1w1; cout = 128; cin = 64;  }
    else if ((idx -= 73728) < 147456) { w = c1w2;   wb = wb_c1w2; cout = 128; cin = 128; }
    else if ((idx -= 147456) < 73728) { w = aux_w;  wb = wb_aux;  cout = 64;  cin = 128; }
    else if ((idx -= 73728) < 73728)  { w = fw1;    wb = wb_fw1;  cout = 64;  cin = 128; }
    else if ((idx -= 73728) < 36864)  { w = fw2;    wb = wb_fw2;  cout = 64;  cin = 64;  }
    else if ((idx -= 36864) < 36864) {
        int o = idx / 576, rem = idx % 576;
        int c = rem / 9, k = rem - c * 9;
        int K = k * 64 + c;
        wdefb2[((size_t)((K >> 5) * 64 + o)) * 32 + (K & 31)] = f2bf(dcn_w[idx]);
        return;
    } else return;
    int o = idx / (cin * 9);
    int rem = idx - o * cin * 9;
    int c = rem / 9;
    int t = rem - c * 9;
    int nch = cin >> 5;
    wb[((t * nch + (c >> 5)) * cout + o) * 32 + (c & 31)] = f2bf(w[idx]);
}

// ---------- transpose f32 NCHW -> bf16 cl32 (mv+ref) AND cl8 (ref only) ----------
__global__ __launch_bounds__(256) void transpose_all(
    const float* __restrict__ mv, const float* __restrict__ ref,
    unsigned short* __restrict__ mvb, unsigned short* __restrict__ refb,
    unsigned short* __restrict__ refb8)
{
    __shared__ float tile[32][68];
    const int tid = threadIdx.x;
    int bz = blockIdx.z;
    const float* in; unsigned short* outb;
    bool isRef = (bz >= 16);
    int bzr = isRef ? bz - 16 : bz;
    if (isRef) { in = ref; outb = refb; }
    else       { in = mv;  outb = mvb;  }
    const int y = blockIdx.y;
    const int x0 = blockIdx.x * 64;
#pragma unroll
    for (int it = 0; it < 2; ++it) {
        int u = tid + it * 256;
        int c = u >> 4, q = u & 15;
        float4 v = *(const float4*)(in + (((size_t)bzr * 32 + c) * HH + y) * WW + x0 + q * 4);
        *(float4*)&tile[c][q * 4] = v;
    }
    __syncthreads();
    const int pxl = tid >> 2, c8 = tid & 3;
    bf16x8 ov;
#pragma unroll
    for (int j = 0; j < 8; ++j) ov[j] = (short)f2bf(tile[c8 * 8 + j][pxl]);
    *(bf16x8*)(outb + (((size_t)bzr * HH + y) * WW + x0 + pxl) * 32 + c8 * 8) = ov;
    if (isRef) {
        *(bf16x8*)(refb8 + ((size_t)(bzr * 4 + c8) * HWSZ + (size_t)y * WW + x0 + pxl) * 8) = ov;
    }
}

// ---------- 3x3 conv v10: input AND weights staged in LDS per chunk ----------
template<int CIN, int COUT_TILE, bool RELU, int EPI>
__global__ __launch_bounds__(256, 3) void conv3x3_v10(
    const unsigned short* __restrict__ in, const unsigned short* __restrict__ wb,
    const float* __restrict__ bias, void* __restrict__ outp,
    int cTot, int ocBase, int nOc, int coutFull, int nPerXcd)
{
    constexpr int NCH = CIN / 32;
    constexpr int NOC = COUT_TILE / 16;
    constexpr int WGR = 36 * COUT_TILE;
    __shared__ __align__(16) unsigned short sx[6 * 72 * 32];
    __shared__ __align__(16) unsigned short sw[288 * COUT_TILE];

    const int tid = threadIdx.x;
    const int d = blockIdx.x;
    const int w = (d & 7) * nPerXcd + (d >> 3);
    const int ocT = (w % nOc) * COUT_TILE;
    int t = w / nOc;
    const int x0 = (t % 3) * 64; t /= 3;
    const int y0 = (t % 48) * 4;
    const int b  = t / 48;
    const int wv = tid >> 6, lane = tid & 63;
    const int l15 = lane & 15, kg = lane >> 4;

    f32x4 acc[NOC][4];
#pragma unroll
    for (int oc = 0; oc < NOC; ++oc)
#pragma unroll
        for (int s = 0; s < 4; ++s) acc[oc][s] = (f32x4){0.f, 0.f, 0.f, 0.f};

    for (int ch = 0; ch < NCH; ++ch) {
#pragma unroll
        for (int it = 0; it < 7; ++it) {
            int u = tid + it * 256;
            if (u < 1728) {
                int r = u / 288;
                int rem = u - r * 288;
                int px = rem >> 2, c8 = rem & 3;
                int yin = y0 - 1 + r;
                int gx  = x0 - 4 + px;
                bf16x8 v = {0,0,0,0,0,0,0,0};
                if (yin >= 0 && yin < HH && gx >= 0 && gx < WW)
                    v = *(const bf16x8*)(in + (((size_t)(b * NCH + ch) * HH + yin) * WW + gx) * 32 + c8 * 8);
                *(bf16x8*)&sx[(r * 72 + px) * 32 + ((c8 ^ ((px >> 1) & 3)) << 3)] = v;
            }
        }
#pragma unroll
        for (int it = 0; it < 7; ++it) {
            int u = tid + it * 256;
            if (u < WGR) {
                int tap = u / (4 * COUT_TILE);
                int rem = u - tap * 4 * COUT_TILE;
                int kgi = rem / COUT_TILE;
                int row = rem - kgi * COUT_TILE;
                bf16x8 v = *(const bf16x8*)(wb
                    + ((size_t)((tap * NCH + ch) * coutFull) + ocT + row) * 32 + kgi * 8);
                *(bf16x8*)&sw[((tap * 4 + kgi) * COUT_TILE + row) * 8] = v;
            }
        }
        __syncthreads();
#pragma unroll
        for (int ky = 0; ky < 3; ++ky) {
#pragma unroll
            for (int kx = 0; kx < 3; ++kx) {
                const int r = wv + ky;
                const int tap = ky * 3 + kx;
                bf16x8 bf[4];
#pragma unroll
                for (int s = 0; s < 4; ++s) {
                    int p = s * 16 + l15 + kx + 3;
                    bf[s] = *(const bf16x8*)&sx[(r * 72 + p) * 32 + ((kg ^ ((p >> 1) & 3)) << 3)];
                }
#pragma unroll
                for (int oc = 0; oc < NOC; ++oc) {
                    bf16x8 a = *(const bf16x8*)&sw[((tap * 4 + kg) * COUT_TILE + oc * 16 + l15) * 8];
#pragma unroll
                    for (int s = 0; s < 4; ++s)
                        acc[oc][s] = __builtin_amdgcn_mfma_f32_16x16x32_bf16(a, bf[s], acc[oc][s], 0, 0, 0);
                }
            }
        }
        __syncthreads();
    }
    const int y = y0 + wv;
    if (EPI == 1) {
        float* out = (float*)outp;
#pragma unroll
        for (int oc = 0; oc < NOC; ++oc)
#pragma unroll
            for (int s = 0; s < 4; ++s) {
                int xo = x0 + s * 16 + l15;
#pragma unroll
                for (int j = 0; j < 4; ++j) {
                    int oL = ocT + oc * 16 + kg * 4 + j;
                    float rv = acc[oc][s][j] + bias[oL];
                    if (RELU) rv = fmaxf(rv, 0.f);
                    out[((size_t)(b * cTot + ocBase + oL) * HH + y) * WW + xo] = rv;
                }
            }
    } else if (EPI == 2) {
        unsigned short* out = (unsigned short*)outp;
#pragma unroll
        for (int oc = 0; oc < NOC; ++oc)
#pragma unroll
            for (int s = 0; s < 4; ++s) {
                int xo = x0 + s * 16 + l15;
#pragma unroll
                for (int j = 0; j < 4; ++j) {
                    int oL = ocT + oc * 16 + kg * 4 + j;
                    float rv = acc[oc][s][j] + bias[oL];
                    if (RELU) rv = fmaxf(rv, 0.f);
                    out[((size_t)(b * cTot + ocBase + oL) * HH + y) * WW + xo] = f2bf(rv);
                }
            }
    } else {
        unsigned short* out = (unsigned short*)outp;
#pragma unroll
        for (int oc = 0; oc < NOC; ++oc) {
            int oL = ocT + oc * 16 + kg * 4;
            int o0 = ocBase + oL;
#pragma unroll
            for (int s = 0; s < 4; ++s) {
                int xo = x0 + s * 16 + l15;
                ushort4 u;
                float r0 = acc[oc][s][0] + bias[oL + 0];
                float r1 = acc[oc][s][1] + bias[oL + 1];
                float r2 = acc[oc][s][2] + bias[oL + 2];
                float r3 = acc[oc][s][3] + bias[oL + 3];
                if (RELU) { r0 = fmaxf(r0,0.f); r1 = fmaxf(r1,0.f); r2 = fmaxf(r2,0.f); r3 = fmaxf(r3,0.f); }
                u.x = f2bf(r0); u.y = f2bf(r1); u.z = f2bf(r2); u.w = f2bf(r3);
                *(ushort4*)(out + ((((size_t)(b * cTot + (o0 >> 5)) * HH + y) * WW + xo) * 32) + (o0 & 31)) = u;
            }
        }
    }
}

// ---------- deformable conv v7: cl8 ref layout ----------
__global__ __launch_bounds__(512, 4) void deform_v7(
    const unsigned short* __restrict__ xb8, const unsigned short* __restrict__ offb,
    const unsigned short* __restrict__ wdefb2, const float* __restrict__ bias,
    unsigned short* __restrict__ cat)
{
    __shared__ __align__(16) unsigned short smp[64 * 584];
    const int tid = threadIdx.x;
    const int b = blockIdx.z;
    int flat = blockIdx.x;
    int nf = (flat & 7) * 72 + (flat >> 3);
    const int pixbase = nf * 64;

    const int px = tid & 63, g = tid >> 6;
    const int pix = pixbase + px;
    const int y = pix / WW, x = pix - y * WW;

    const char* xgb = (const char*)(xb8 + (size_t)(b * 8 + g) * HWSZ * 8);
    const unsigned short* ob = offb + ((size_t)(b * 144 + g * 18)) * HWSZ + pix;

    float dyv[9], dxv[9];
#pragma unroll
    for (int k = 0; k < 9; ++k) {
        dyv[k] = bf2f(ob[(size_t)(2 * k) * HWSZ]);
        dxv[k] = bf2f(ob[(size_t)(2 * k + 1) * HWSZ]);
    }

    auto calc = [&](int k, int vo[4], float w4[4]) {
        float pyf = (float)(y + k / 3 - 1) + dyv[k];
        float pxf = (float)(x + k % 3 - 1) + dxv[k];
        float fy = floorf(pyf), fx = floorf(pxf);
        float wy = pyf - fy, wx = pxf - fx;
        int iy = (int)fy, ix = (int)fx;
        float w00 = (1.f - wy) * (1.f - wx), w01 = (1.f - wy) * wx;
        float w10 = wy * (1.f - wx),         w11 = wy * wx;
        bool y0v = (iy >= 0) && (iy < HH);
        bool y1v = (iy + 1 >= 0) && (iy + 1 < HH);
        bool x0v = (ix >= 0) && (ix < WW);
        bool x1v = (ix + 1 >= 0) && (ix + 1 < WW);
        if (!(y0v && x0v)) w00 = 0.f;
        if (!(y0v && x1v)) w01 = 0.f;
        if (!(y1v && x0v)) w10 = 0.f;
        if (!(y1v && x1v)) w11 = 0.f;
        int cy0 = min(max(iy, 0), HH - 1), cy1 = min(max(iy + 1, 0), HH - 1);
        int cx0 = min(max(ix, 0), WW - 1), cx1 = min(max(ix + 1, 0), WW - 1);
        vo[0] = (cy0 * WW + cx0) * 16;
        vo[1] = (cy0 * WW + cx1) * 16;
        vo[2] = (cy1 * WW + cx0) * 16;
        vo[3] = (cy1 * WW + cx1) * 16;
        w4[0] = w00; w4[1] = w01; w4[2] = w10; w4[3] = w11;
    };

    float wr[3][4];
    bf16x8 pf[2][4];
    {
        int vo[4]; calc(0, vo, wr[0]);
#pragma unroll
        for (int j = 0; j < 4; ++j) pf[0][j] = *(const bf16x8*)(xgb + vo[j]);
    }
    {
        int vo[4]; calc(1, vo, wr[1]);
#pragma unroll
        for (int j = 0; j < 4; ++j) pf[1][j] = *(const bf16x8*)(xgb + vo[j]);
    }
    unsigned short* so = smp + px * 584 + g * 8;
#pragma unroll
    for (int k = 0; k < 9; ++k) {
        bf16x8 nx0, nx1, nx2, nx3;
        if (k + 2 < 9) {
            int vo[4]; calc(k + 2, vo, wr[(k + 2) % 3]);
            nx0 = *(const bf16x8*)(xgb + vo[0]);
            nx1 = *(const bf16x8*)(xgb + vo[1]);
            nx2 = *(const bf16x8*)(xgb + vo[2]);
            nx3 = *(const bf16x8*)(xgb + vo[3]);
        }
        __builtin_amdgcn_sched_barrier(0);
        bf16x8 ov;
#pragma unroll
        for (int cc = 0; cc < 8; ++cc) {
            float s = bf2f((unsigned short)pf[k & 1][0][cc]) * wr[k % 3][0]
                    + bf2f((unsigned short)pf[k & 1][1][cc]) * wr[k % 3][1]
                    + bf2f((unsigned short)pf[k & 1][2][cc]) * wr[k % 3][2]
                    + bf2f((unsigned short)pf[k & 1][3][cc]) * wr[k % 3][3];
            ov[cc] = (short)f2bf(s);
        }
        *(bf16x8*)(so + k * 64) = ov;
        if (k + 2 < 9) { pf[k & 1][0] = nx0; pf[k & 1][1] = nx1; pf[k & 1][2] = nx2; pf[k & 1][3] = nx3; }
    }
    __syncthreads();
    const int wv = tid >> 6;
    const int lane = tid & 63, l15 = lane & 15, kg = lane >> 4;
    const int oc = wv >> 1, sp = (wv & 1) * 2;
    f32x4 acc0 = (f32x4){0.f, 0.f, 0.f, 0.f};
    f32x4 acc1 = (f32x4){0.f, 0.f, 0.f, 0.f};
    const unsigned short* arow = wdefb2 + ((size_t)(oc * 16 + l15)) * 32 + kg * 8;
#pragma unroll
    for (int ch = 0; ch < 18; ++ch) {
        bf16x8 b0 = *(const bf16x8*)&smp[(sp * 16 + l15) * 584 + ch * 32 + kg * 8];
        bf16x8 b1 = *(const bf16x8*)&smp[((sp + 1) * 16 + l15) * 584 + ch * 32 + kg * 8];
        bf16x8 a = *(const bf16x8*)(arow + (size_t)ch * 64 * 32);
        acc0 = __builtin_amdgcn_mfma_f32_16x16x32_bf16(a, b0, acc0, 0, 0, 0);
        acc1 = __builtin_amdgcn_mfma_f32_16x16x32_bf16(a, b1, acc1, 0, 0, 0);
    }
    const int o0 = oc * 16 + kg * 4;
#pragma unroll
    for (int s = 0; s < 2; ++s) {
        const f32x4& av = s ? acc1 : acc0;
        int pxo = pixbase + (sp + s) * 16 + l15;
        int yo = pxo / WW, xo = pxo - yo * WW;
        ushort4 u;
        u.x = f2bf(fmaxf(av[0] + bias[o0 + 0], 0.f));
        u.y = f2bf(fmaxf(av[1] + bias[o0 + 1], 0.f));
        u.z = f2bf(fmaxf(av[2] + bias[o0 + 2], 0.f));
        u.w = f2bf(fmaxf(av[3] + bias[o0 + 3], 0.f));
        *(ushort4*)(cat + ((((size_t)(b * 4 + (o0 >> 5)) * HH + yo) * WW + xo) * 32) + (o0 & 31)) = u;
    }
}

// ---------------- global average pool ----------------
__global__ __launch_bounds__(256) void pool_kernel(const float* __restrict__ x, float* __restrict__ gout)
{
    int bc = blockIdx.x;
    const float* p = x + (size_t)bc * HWSZ;
    int tid = threadIdx.x;
    float s = 0.f;
    for (int i = tid * 4; i < HWSZ; i += 256 * 4) {
        float4 v = *reinterpret_cast<const float4*>(p + i);
        s += v.x + v.y + v.z + v.w;
    }
#pragma unroll
    for (int o = 32; o > 0; o >>= 1) s += __shfl_down(s, o, 64);
    __shared__ float red[4];
    if ((tid & 63) == 0) red[tid >> 6] = s;
    __syncthreads();
    if (tid == 0) gout[bc] = (red[0] + red[1] + red[2] + red[3]) * (1.f / (float)HWSZ);
}

// ---------------- SE MLP ----------------
__global__ __launch_bounds__(256) void se_kernel(
    const float* __restrict__ g, const float* __restrict__ w1, const float* __restrict__ b1,
    const float* __restrict__ w2, const float* __restrict__ b2, float* __restrict__ a)
{
    __shared__ float sg[BB * 64];
    __shared__ float sh[BB * 32];
    int tid = threadIdx.x;
    sg[tid] = g[tid];
    __syncthreads();
    if (tid < BB * 32) {
        int b = tid / 32, h = tid % 32;
        float s = b1[h];
        for (int c = 0; c < 64; ++c) s += sg[b * 64 + c] * w1[h * 64 + c];
        sh[b * 32 + h] = fmaxf(s, 0.f);
    }
    __syncthreads();
    {
        int b = tid / 64, o = tid % 64;
        float s = b2[o];
        for (int h = 0; h < 32; ++h) s += sh[b * 32 + h] * w2[o * 32 + h];
        a[tid] = 1.f / (1.f + expf(-s));
    }
}

// ---------------- residual (bf16 cl32 def) + SE scale ----------------
__global__ __launch_bounds__(256) void final_v2(
    float* __restrict__ out, const unsigned short* __restrict__ catb, const float* __restrict__ a)
{
    const int VPC = HWSZ / 4;
    int v = blockIdx.x * 256 + threadIdx.x;
    int bc = v / VPC, within = v - bc * VPC;
    int b = bc >> 6, c = bc & 63;
    float av = a[bc];
    int pix = within * 4;
    int y = pix / WW, x = pix - y * WW;
    const unsigned short* dbase = catb
        + (((size_t)(b * 4 + (c >> 5)) * HH + y) * WW + x) * 32 + (c & 31);
    float4 xo = reinterpret_cast<float4*>(out)[v];
    float4 r;
    r.x = bf2f(dbase[0])  + xo.x * av;
    r.y = bf2f(dbase[32]) + xo.y * av;
    r.z = bf2f(dbase[64]) + xo.z * av;
    r.w = bf2f(dbase[96]) + xo.w * av;
    reinterpret_cast<float4*>(out)[v] = r;
}

extern "C" void kernel_launch(void* const* d_in, const int* in_sizes, int n_in,
                              void* d_out, int out_size, void* d_ws, size_t ws_size,
                              hipStream_t stream) {
    const float* mv     = (const float*)d_in[0];
    const float* ref    = (const float*)d_in[1];
    const float* head_w = (const float*)d_in[2];
    const float* head_b = (const float*)d_in[3];
    const float* dcn_w  = (const float*)d_in[4];
    const float* dcn_b  = (const float*)d_in[5];
    const float* c1w1   = (const float*)d_in[6];
    const float* c1b1   = (const float*)d_in[7];
    const float* c1w2   = (const float*)d_in[8];
    const float* c1b2   = (const float*)d_in[9];
    const float* aux_w  = (const float*)d_in[10];
    const float* aux_b  = (const float*)d_in[11];
    const float* fw1    = (const float*)d_in[12];
    const float* fb1    = (const float*)d_in[13];
    const float* fw2    = (const float*)d_in[14];
    const float* fb2    = (const float*)d_in[15];
    const float* se_w1  = (const float*)d_in[16];
    const float* se_b1  = (const float*)d_in[17];
    const float* se_w2  = (const float*)d_in[18];
    const float* se_b2  = (const float*)d_in[19];
    float* out = (float*)d_out;

    float* ws = (float*)d_ws;
    unsigned short* offb     = (unsigned short*)ws;                  // 21,233,664 sh (bf16 offsets)
    unsigned short* mvb      = (unsigned short*)(ws + 21233664);     // 18,874,368 sh
    unsigned short* refb     = (unsigned short*)(ws + 30670848);     //  9,437,184 sh
    unsigned short* catb     = (unsigned short*)(ws + 35389440);     // 18,874,368 sh
    unsigned short* r2b      = (unsigned short*)(ws + 44826624);     // 18,874,368 sh
    unsigned short* wdefb2   = (unsigned short*)(ws + 54263808);     //     36,864 sh
    unsigned short* wbb      = (unsigned short*)(ws + 54282240);     //    571,392 sh
    unsigned short* refb8    = wbb + 571392;                         //  9,437,184 sh (cl8 ref)
    float* gbuf              = (float*)(refb8 + 9437184 + 16);
    float* abuf              = gbuf + 256;
    unsigned short* t1b      = (unsigned short*)ws;                  // reuse off region after deform

    unsigned short* wb_head = wbb;                    // 144*128*9
    unsigned short* wb_c1w1 = wb_head + 165888;       // 128*64*9
    unsigned short* wb_c1w2 = wb_c1w1 + 73728;        // 128*128*9
    unsigned short* wb_aux  = wb_c1w2 + 147456;       // 64*128*9
    unsigned short* wb_fw1  = wb_aux  + 73728;        // 64*128*9
    unsigned short* wb_fw2  = wb_fw1  + 73728;        // 64*64*9

    prep_all<<<2376, 256, 0, stream>>>(head_w, c1w1, c1w2, aux_w, fw1, fw2, dcn_w,
                                       wb_head, wb_c1w1, wb_c1w2, wb_aux, wb_fw1, wb_fw2, wdefb2);
    transpose_all<<<dim3(3, 192, 24), 256, 0, stream>>>(mv, ref, mvb, refb, refb8);

    // 1. offsets = conv(mv)                    128 -> 144   (bf16 NCHW, 3 oc-tiles of 48)
    conv3x3_v10<128, 48, false, 2><<<1728, 256, 0, stream>>>(
        mvb, wb_head, head_b, offb, 144, 0, 3, 144, 216);
    // 2. def_feat = relu(deform(ref cl8, offsets)) -> catb chunks 0-1
    deform_v7<<<dim3(576, 1, BB), 512, 0, stream>>>(refb8, offb, wdefb2, dcn_b, catb);
    // 3. t1 = relu(conv(ref, c1w1))            64 -> 128    (4 oc-tiles of 32)
    conv3x3_v10<64, 32, true, 0><<<2304, 256, 0, stream>>>(
        refb, wb_c1w1, c1b1, t1b, 4, 0, 4, 128, 288);
    // 4. aux_in = relu(conv(t1, c1w2))         128 -> 128   (4 oc-tiles of 32)
    conv3x3_v10<128, 32, true, 0><<<2304, 256, 0, stream>>>(
        t1b, wb_c1w2, c1b2, r2b, 4, 0, 4, 128, 288);
    // 5. aux = relu(conv(aux_in, aux_w))       128 -> 64    -> catb chunks 2-3 (2 tiles of 32)
    conv3x3_v10<128, 32, true, 0><<<1152, 256, 0, stream>>>(
        r2b, wb_aux, aux_b, catb, 4, 64, 2, 64, 144);
    // 6. x1 = relu(conv(cat, fw1))             128 -> 64    (2 tiles of 32)
    conv3x3_v10<128, 32, true, 0><<<1152, 256, 0, stream>>>(
        catb, wb_fw1, fb1, r2b, 2, 0, 2, 64, 144);
    // 7. x2 = conv(x1, fw2)                    64 -> 64     -> d_out (f32 NCHW, 2 tiles of 32)
    conv3x3_v10<64, 32, false, 1><<<1152, 256, 0, stream>>>(
        r2b, wb_fw2, fb2, out, 64, 0, 2, 64, 144);
    // 8-10. pool, SE, residual
    pool_kernel<<<BB * 64, 256, 0, stream>>>(out, gbuf);
    se_kernel<<<1, 256, 0, stream>>>(gbuf, se_w1, se_b1, se_w2, se_b2, abuf);
    final_v2<<<9216, 256, 0, stream>>>(out, catb, abuf);
}